// Round 9
// baseline (518.477 us; speedup 1.0000x reference)
//
#include <hip/hip_runtime.h>
#include <stdint.h>

// ---------------- types ----------------
using i32x4 = __attribute__((ext_vector_type(4))) int;
using f32x4 = __attribute__((ext_vector_type(4))) float;
using f16x4 = __attribute__((ext_vector_type(4))) _Float16;

#define M_TOK 8192
#define N_EMB 1024
#define D_FF  4096

__device__ __forceinline__ void async_lds16(void* lds, const void* g) {
  __builtin_amdgcn_global_load_lds(
      (const __attribute__((address_space(1))) void*)g,
      (__attribute__((address_space(3))) void*)lds, 16, 0, 0);
}

// ---------------- tiny init ----------------
__global__ void zero_slots_k(unsigned* s) {
  if (threadIdx.x < 16) s[threadIdx.x] = 0u;
}

// ---------------- global absmax ----------------
__global__ void absmax_k(const float* __restrict__ p, long n, unsigned* __restrict__ slot) {
  long i = ((long)blockIdx.x * blockDim.x + threadIdx.x) * 4;
  long stride = (long)gridDim.x * blockDim.x * 4;
  float m = 0.f;
  for (; i < n; i += stride) {
    float4 v = *(const float4*)(p + i);
    m = fmaxf(m, fmaxf(fmaxf(fabsf(v.x), fabsf(v.y)), fmaxf(fabsf(v.z), fabsf(v.w))));
  }
  for (int o = 32; o; o >>= 1) m = fmaxf(m, __shfl_xor(m, o));
  __shared__ float sm[4];
  if ((threadIdx.x & 63) == 0) sm[threadIdx.x >> 6] = m;
  __syncthreads();
  if (threadIdx.x == 0) {
    m = fmaxf(fmaxf(sm[0], sm[1]), fmaxf(sm[2], sm[3]));
    atomicMax(slot, __float_as_uint(m));
  }
}

// ---------------- plain int8 quantization (weights) ----------------
__global__ void quant_k(const float* __restrict__ p, int8_t* __restrict__ q, long n,
                        const unsigned* __restrict__ slot) {
  float inv = 127.f / fmaxf(__uint_as_float(*slot), 1e-8f);
  long i = ((long)blockIdx.x * blockDim.x + threadIdx.x) * 4;
  long stride = (long)gridDim.x * blockDim.x * 4;
  for (; i < n; i += stride) {
    float4 v = *(const float4*)(p + i);
    int b0 = (int)fminf(fmaxf(rintf(v.x * inv), -127.f), 127.f);
    int b1 = (int)fminf(fmaxf(rintf(v.y * inv), -127.f), 127.f);
    int b2 = (int)fminf(fmaxf(rintf(v.z * inv), -127.f), 127.f);
    int b3 = (int)fminf(fmaxf(rintf(v.w * inv), -127.f), 127.f);
    int w = (b0 & 0xff) | ((b1 & 0xff) << 8) | ((b2 & 0xff) << 16) | ((b3 & 0xff) << 24);
    *(int*)(q + i) = w;
  }
}

// ---------------- pre-swizzle LoRA-down A[16][K] into per-lane MFMA B-fragments ----------------
__global__ void prep_bfrag_k(const float* __restrict__ A, _Float16* __restrict__ Bp, int K) {
  int s = blockIdx.x;
  int l = threadIdx.x;  // 64 threads
  int r = l & 15, g = l >> 4;
  float4 v = *(const float4*)(A + (long)r * K + s * 16 + g * 4);
  f16x4 h;
  h[0] = (_Float16)v.x; h[1] = (_Float16)v.y; h[2] = (_Float16)v.z; h[3] = (_Float16)v.w;
  *(f16x4*)(Bp + ((long)s * 64 + l) * 4) = h;
}

// ---------------- fused: quantize X rows to int8 AND T = 2 * X @ A^T via f16 MFMA ----------------
__global__ __launch_bounds__(512) void lora_quant_k(
    const float* __restrict__ X, const _Float16* __restrict__ Bpre,
    const unsigned* __restrict__ slot, int8_t* __restrict__ Q,
    float* __restrict__ T, int K) {
  int lane = threadIdx.x & 63, wave = threadIdx.x >> 6;
  int row0 = blockIdx.x * 16;
  int r = lane & 15, g = lane >> 4;
  float inv = 127.f / fmaxf(__uint_as_float(*slot), 1e-8f);

  int kPerWave = K >> 3;
  int kbase = wave * kPerWave;
  const float* xrow = X + (long)(row0 + r) * K;
  int8_t* qrow = Q + (long)(row0 + r) * K;

  f32x4 acc = {0.f, 0.f, 0.f, 0.f};
  int nsteps = kPerWave >> 4;
#pragma unroll 4
  for (int s = 0; s < nsteps; s++) {
    int k = kbase + s * 16 + g * 4;
    float4 v = *(const float4*)(xrow + k);
    int b0 = (int)fminf(fmaxf(rintf(v.x * inv), -127.f), 127.f);
    int b1 = (int)fminf(fmaxf(rintf(v.y * inv), -127.f), 127.f);
    int b2 = (int)fminf(fmaxf(rintf(v.z * inv), -127.f), 127.f);
    int b3 = (int)fminf(fmaxf(rintf(v.w * inv), -127.f), 127.f);
    *(int*)(qrow + k) = (b0 & 0xff) | ((b1 & 0xff) << 8) | ((b2 & 0xff) << 16) | ((b3 & 0xff) << 24);
    f16x4 a;
    a[0] = (_Float16)v.x; a[1] = (_Float16)v.y; a[2] = (_Float16)v.z; a[3] = (_Float16)v.w;
    int gs = (kbase + s * 16) >> 4;
    f16x4 b = *(const f16x4*)(Bpre + ((long)gs * 64 + lane) * 4);
    acc = __builtin_amdgcn_mfma_f32_16x16x16f16(a, b, acc, 0, 0, 0);
  }

  __shared__ float part[8][16][17];
#pragma unroll
  for (int j = 0; j < 4; j++) part[wave][g * 4 + j][r] = acc[j];
  __syncthreads();
  int t = threadIdx.x;
  if (t < 256) {
    int m = t >> 4, rr = t & 15;
    float sum = 0.f;
#pragma unroll
    for (int w = 0; w < 8; w++) sum += part[w][m][rr];
    T[(long)(row0 + m) * 16 + rr] = 2.0f * sum;  // LORA_SCALE = 32/16 = 2
  }
}

// ---------------- int8 GEMM, thin-phase template ----------------
// BK=64 (64B rows). Per K-tile: 2 thin phases, each {ds_read (4-8 b128) ; lgkmcnt(0)+SB ;
// setprio(1) MFR/2 x NFR MFMA setprio(0) ; barrier}. All 4 staging glls for tile kt+1
// issued at phase 0 of kt (a full tile of latency coverage); single vmcnt(0)+barrier at
// tile top. Buffers ping-pong per tile -> staging never collides with reads.
// LDS key (r^(r>>2))&3 -> fragment b128 reads are 2-way bank-aliased (free, m136).
// GEMM1: BM=BN=256, 512 thr, 64KB LDS -> 2 blocks/CU. GEMM2: 128^2, 256 thr, 32KB.
template <bool GELU, int BM, int BN, int THREADS>
__global__ __launch_bounds__(THREADS, 4) void gemm_tp(
    const int8_t* __restrict__ Aq, const int8_t* __restrict__ Bq,
    int N, int K,
    const unsigned* __restrict__ sa, const unsigned* __restrict__ sb,
    const float* __restrict__ bias,
    const float* __restrict__ T,   // [M][16], pre-scaled by LORA_SCALE
    const float* __restrict__ Bl,  // [N][16]
    float* __restrict__ C, unsigned* hmax) {
  constexpr int WM = 2;
  constexpr int WN = (THREADS / 64) / WM;      // 4 (GEMM1) or 2 (GEMM2)
  constexpr int MFR = BM / WM / 16;            // 8 or 4
  constexpr int NFR = BN / WN / 16;            // 4
  constexpr int MH = MFR / 2;                  // fragments per phase
  constexpr int ABYTES = BM * 64;
  constexpr int BBYTES = BN * 64;
  constexpr int AL = ABYTES / 16 / THREADS;    // glls per thread (A)
  constexpr int BL = BBYTES / 16 / THREADS;
  __shared__ __align__(16) int8_t lds[2 * (ABYTES + BBYTES)];

  // bijective XCD swizzle (nwg = 512 for both grids, %8==0)
  int nwg = gridDim.x * gridDim.y;
  int lid = blockIdx.y * gridDim.x + blockIdx.x;
  int cpx = nwg >> 3;
  int nid = (lid & 7) * cpx + (lid >> 3);
  int bn = (nid % gridDim.x) * BN;
  int bm = (nid / gridDim.x) * BM;

  int t = threadIdx.x;
  int lane = t & 63, wave = t >> 6;
  int wr = wave / WN, wc = wave % WN;
  int l16 = lane & 15, lq = lane >> 4;

  // staging maps: slot s -> row=s>>2, phys col=s&3, global col=(s&3)^key(row)
  int aDst[AL]; const int8_t* srcA[AL];
#pragma unroll
  for (int i = 0; i < AL; i++) {
    int s = i * THREADS + t, row = s >> 2;
    int key = (row ^ (row >> 2)) & 3;
    aDst[i] = s * 16;
    srcA[i] = Aq + (long)(bm + row) * K + (((s & 3) ^ key) << 4);
  }
  int bDst[BL]; const int8_t* srcB[BL];
#pragma unroll
  for (int i = 0; i < BL; i++) {
    int s = i * THREADS + t, row = s >> 2;
    int key = (row ^ (row >> 2)) & 3;
    bDst[i] = s * 16;
    srcB[i] = Bq + (long)(bn + row) * K + (((s & 3) ^ key) << 4);
  }

  // fragment read byte-offsets (swizzled)
  int aoff[MFR], boff[NFR];
#pragma unroll
  for (int mf = 0; mf < MFR; mf++) {
    int row = wr * (BM / WM) + mf * 16 + l16;
    aoff[mf] = row * 64 + ((lq ^ ((row ^ (row >> 2)) & 3)) << 4);
  }
#pragma unroll
  for (int nf = 0; nf < NFR; nf++) {
    int row = wc * (BN / WN) + nf * 16 + l16;
    boff[nf] = row * 64 + ((lq ^ ((row ^ (row >> 2)) & 3)) << 4);
  }

  i32x4 acc[MFR][NFR] = {};
  int KT = K >> 6;

  // prologue: stage tile 0 into buf 0
#pragma unroll
  for (int i = 0; i < AL; i++) async_lds16(lds + aDst[i], srcA[i]);
#pragma unroll
  for (int i = 0; i < BL; i++) async_lds16(lds + ABYTES + bDst[i], srcB[i]);

  for (int kt = 0; kt < KT; ++kt) {
    const int8_t* base = lds + (kt & 1) * (ABYTES + BBYTES);

    asm volatile("s_waitcnt vmcnt(0)" ::: "memory");  // own glls for tile kt landed
    __builtin_amdgcn_s_barrier();                     // everyone's landed

    // ---- phase 0: first M-half + all B fragments
    i32x4 av[MH], bv[NFR];
#pragma unroll
    for (int j = 0; j < MH; j++) av[j] = *(const i32x4*)(base + aoff[j]);
#pragma unroll
    for (int nf = 0; nf < NFR; nf++) bv[nf] = *(const i32x4*)(base + ABYTES + boff[nf]);

    if (kt + 1 < KT) {  // issue ALL of tile kt+1's staging now (full tile of coverage)
      long ko = (long)(kt + 1) * 64;
      int8_t* nb = lds + ((kt + 1) & 1) * (ABYTES + BBYTES);
#pragma unroll
      for (int i = 0; i < AL; i++) async_lds16(nb + aDst[i], srcA[i] + ko);
#pragma unroll
      for (int i = 0; i < BL; i++) async_lds16(nb + ABYTES + bDst[i], srcB[i] + ko);
    }

    asm volatile("s_waitcnt lgkmcnt(0)" ::: "memory");
    __builtin_amdgcn_sched_barrier(0);
    __builtin_amdgcn_s_setprio(1);
#pragma unroll
    for (int j = 0; j < MH; j++)
#pragma unroll
      for (int nf = 0; nf < NFR; nf++)
        acc[j][nf] = __builtin_amdgcn_mfma_i32_16x16x64_i8(av[j], bv[nf], acc[j][nf], 0, 0, 0);
    __builtin_amdgcn_s_setprio(0);
    __builtin_amdgcn_s_barrier();

    // ---- phase 1: second M-half (bv reused from registers)
    i32x4 av2[MH];
#pragma unroll
    for (int j = 0; j < MH; j++) av2[j] = *(const i32x4*)(base + aoff[MH + j]);
    asm volatile("s_waitcnt lgkmcnt(0)" ::: "memory");
    __builtin_amdgcn_sched_barrier(0);
    __builtin_amdgcn_s_setprio(1);
#pragma unroll
    for (int j = 0; j < MH; j++)
#pragma unroll
      for (int nf = 0; nf < NFR; nf++)
        acc[MH + j][nf] = __builtin_amdgcn_mfma_i32_16x16x64_i8(av2[j], bv[nf], acc[MH + j][nf], 0, 0, 0);
    __builtin_amdgcn_s_setprio(0);
    // no barrier here: next tile's top vmcnt(0)+barrier closes the phase
  }

  // -------- epilogue --------
  float s = (fmaxf(__uint_as_float(*sa), 1e-8f) * (1.f / 127.f)) *
            (fmaxf(__uint_as_float(*sb), 1e-8f) * (1.f / 127.f));

  f16x4 af[MFR], bf[NFR];
#pragma unroll
  for (int mf = 0; mf < MFR; mf++) {
    int m = bm + wr * (BM / WM) + mf * 16 + l16;
    float4 tv = *(const float4*)(T + (long)m * 16 + lq * 4);
    f16x4 v; v[0] = (_Float16)tv.x; v[1] = (_Float16)tv.y; v[2] = (_Float16)tv.z; v[3] = (_Float16)tv.w;
    af[mf] = v;
  }
#pragma unroll
  for (int nf = 0; nf < NFR; nf++) {
    int n = bn + wc * (BN / WN) + nf * 16 + l16;
    float4 bv4 = *(const float4*)(Bl + (long)n * 16 + lq * 4);
    f16x4 v; v[0] = (_Float16)bv4.x; v[1] = (_Float16)bv4.y; v[2] = (_Float16)bv4.z; v[3] = (_Float16)bv4.w;
    bf[nf] = v;
  }
  float bias_v[NFR];
#pragma unroll
  for (int nf = 0; nf < NFR; nf++) bias_v[nf] = bias[bn + wc * (BN / WN) + nf * 16 + l16];

  float lmax = 0.f;
#pragma unroll
  for (int mf = 0; mf < MFR; mf++) {
#pragma unroll
    for (int nf = 0; nf < NFR; nf++) {
      f32x4 fa = __builtin_amdgcn_mfma_f32_16x16x16f16(af[mf], bf[nf], f32x4{0.f, 0.f, 0.f, 0.f}, 0, 0, 0);
      int n = bn + wc * (BN / WN) + nf * 16 + l16;
#pragma unroll
      for (int j = 0; j < 4; j++) {
        int m = bm + wr * (BM / WM) + mf * 16 + lq * 4 + j;
        float v = s * (float)acc[mf][nf][j] + bias_v[nf] + fa[j];
        if constexpr (GELU) {
          v = 0.5f * v * (1.0f + erff(v * 0.70710678118654752f));
          lmax = fmaxf(lmax, fabsf(v));
        }
        C[(long)m * N + n] = v;
      }
    }
  }
  if constexpr (GELU) {
    for (int o = 32; o; o >>= 1) lmax = fmaxf(lmax, __shfl_xor(lmax, o));
    if (lane == 0) atomicMax(hmax, __float_as_uint(lmax));
  }
}

// ---------------- launch ----------------
extern "C" void kernel_launch(void* const* d_in, const int* in_sizes, int n_in,
                              void* d_out, int out_size, void* d_ws, size_t ws_size,
                              hipStream_t stream) {
  const float* x   = (const float*)d_in[0];
  const float* Wfc = (const float*)d_in[1];
  const float* bfc = (const float*)d_in[2];
  const float* Afc = (const float*)d_in[3];
  const float* Bfc = (const float*)d_in[4];
  const float* Wpj = (const float*)d_in[5];
  const float* bpj = (const float*)d_in[6];
  const float* Apj = (const float*)d_in[7];
  const float* Bpj = (const float*)d_in[8];
  float* out = (float*)d_out;

  char* ws = (char*)d_ws;
  unsigned* slots = (unsigned*)ws;  // [0]=max|x| [1]=max|Wfc| [2]=max|Wpj| [3]=max|h|
  int8_t* qx  = (int8_t*)(ws + 256);
  int8_t* qwf = qx  + (size_t)M_TOK * N_EMB;
  int8_t* qwp = qwf + (size_t)D_FF * N_EMB;
  int8_t* qh  = qwp + (size_t)N_EMB * D_FF;
  float*  t1  = (float*)(qh + (size_t)M_TOK * D_FF);
  float*  t2  = t1  + (size_t)M_TOK * 16;
  _Float16* Bp1 = (_Float16*)(t2 + (size_t)M_TOK * 16);
  _Float16* Bp2 = Bp1 + (size_t)N_EMB * 16;
  float*  h   = (float*)(Bp2 + (size_t)D_FF * 16);

  zero_slots_k<<<1, 64, 0, stream>>>(slots);
  absmax_k<<<1024, 256, 0, stream>>>(x,   (long)M_TOK * N_EMB, slots + 0);
  absmax_k<<<1024, 256, 0, stream>>>(Wfc, (long)D_FF * N_EMB,  slots + 1);
  absmax_k<<<1024, 256, 0, stream>>>(Wpj, (long)N_EMB * D_FF,  slots + 2);

  quant_k<<<2048, 256, 0, stream>>>(Wfc, qwf, (long)D_FF * N_EMB, slots + 1);
  quant_k<<<2048, 256, 0, stream>>>(Wpj, qwp, (long)N_EMB * D_FF, slots + 2);

  prep_bfrag_k<<<N_EMB / 16, 64, 0, stream>>>(Afc, Bp1, N_EMB);
  prep_bfrag_k<<<D_FF / 16, 64, 0, stream>>>(Apj, Bp2, D_FF);

  lora_quant_k<<<M_TOK / 16, 512, 0, stream>>>(x, Bp1, slots + 0, qx, t1, N_EMB);

  // GEMM1: 256x256 tiles -> grid (16, 32) = 512 blocks, 2 blocks/CU
  gemm_tp<true, 256, 256, 512><<<dim3(D_FF / 256, M_TOK / 256), 512, 0, stream>>>(
      qx, qwf, D_FF, N_EMB, slots + 0, slots + 1, bfc, t1, Bfc, h, slots + 3);

  lora_quant_k<<<M_TOK / 16, 512, 0, stream>>>(h, Bp2, slots + 3, qh, t2, D_FF);

  // GEMM2: 128x128 tiles -> grid (8, 64) = 512 blocks, 2 blocks/CU
  gemm_tp<false, 128, 128, 256><<<dim3(N_EMB / 128, M_TOK / 128), 256, 0, stream>>>(
      qh, qwp, N_EMB, D_FF, slots + 3, slots + 2, bpj, t2, Bpj, out, nullptr);
}

// Round 10
// 286.068 us; speedup vs baseline: 1.8124x; 1.8124x over previous
//
#include <hip/hip_runtime.h>
#include <stdint.h>

// ---------------- types ----------------
using i32x4  = __attribute__((ext_vector_type(4))) int;
using i32x16 = __attribute__((ext_vector_type(16))) int;
using f32x4  = __attribute__((ext_vector_type(4))) float;
using f32x16 = __attribute__((ext_vector_type(16))) float;
using f16x4  = __attribute__((ext_vector_type(4))) _Float16;
using f16x8  = __attribute__((ext_vector_type(8))) _Float16;

#define M_TOK 8192
#define N_EMB 1024
#define D_FF  4096

__device__ __forceinline__ void async_lds16(void* lds, const void* g) {
  __builtin_amdgcn_global_load_lds(
      (const __attribute__((address_space(1))) void*)g,
      (__attribute__((address_space(3))) void*)lds, 16, 0, 0);
}

// ---------------- tiny init ----------------
__global__ void zero_slots_k(unsigned* s) {
  if (threadIdx.x < 16) s[threadIdx.x] = 0u;
}

// ---------------- global absmax ----------------
__global__ void absmax_k(const float* __restrict__ p, long n, unsigned* __restrict__ slot) {
  long i = ((long)blockIdx.x * blockDim.x + threadIdx.x) * 4;
  long stride = (long)gridDim.x * blockDim.x * 4;
  float m = 0.f;
  for (; i < n; i += stride) {
    float4 v = *(const float4*)(p + i);
    m = fmaxf(m, fmaxf(fmaxf(fabsf(v.x), fabsf(v.y)), fmaxf(fabsf(v.z), fabsf(v.w))));
  }
  for (int o = 32; o; o >>= 1) m = fmaxf(m, __shfl_xor(m, o));
  __shared__ float sm[4];
  if ((threadIdx.x & 63) == 0) sm[threadIdx.x >> 6] = m;
  __syncthreads();
  if (threadIdx.x == 0) {
    m = fmaxf(fmaxf(sm[0], sm[1]), fmaxf(sm[2], sm[3]));
    atomicMax(slot, __float_as_uint(m));
  }
}

// ---------------- plain int8 quantization (weights) ----------------
__global__ void quant_k(const float* __restrict__ p, int8_t* __restrict__ q, long n,
                        const unsigned* __restrict__ slot) {
  float inv = 127.f / fmaxf(__uint_as_float(*slot), 1e-8f);
  long i = ((long)blockIdx.x * blockDim.x + threadIdx.x) * 4;
  long stride = (long)gridDim.x * blockDim.x * 4;
  for (; i < n; i += stride) {
    float4 v = *(const float4*)(p + i);
    int b0 = (int)fminf(fmaxf(rintf(v.x * inv), -127.f), 127.f);
    int b1 = (int)fminf(fmaxf(rintf(v.y * inv), -127.f), 127.f);
    int b2 = (int)fminf(fmaxf(rintf(v.z * inv), -127.f), 127.f);
    int b3 = (int)fminf(fmaxf(rintf(v.w * inv), -127.f), 127.f);
    int w = (b0 & 0xff) | ((b1 & 0xff) << 8) | ((b2 & 0xff) << 16) | ((b3 & 0xff) << 24);
    *(int*)(q + i) = w;
  }
}

// ---------------- pre-swizzle LoRA-down A[16][K] into per-lane MFMA B-fragments ----------------
__global__ void prep_bfrag_k(const float* __restrict__ A, _Float16* __restrict__ Bp, int K) {
  int s = blockIdx.x;
  int l = threadIdx.x;  // 64 threads
  int r = l & 15, g = l >> 4;
  float4 v = *(const float4*)(A + (long)r * K + s * 16 + g * 4);
  f16x4 h;
  h[0] = (_Float16)v.x; h[1] = (_Float16)v.y; h[2] = (_Float16)v.z; h[3] = (_Float16)v.w;
  *(f16x4*)(Bp + ((long)s * 64 + l) * 4) = h;
}

// ---------------- fused: quantize X rows to int8 AND T = 2 * X @ A^T via f16 MFMA ----------------
__global__ __launch_bounds__(512) void lora_quant_k(
    const float* __restrict__ X, const _Float16* __restrict__ Bpre,
    const unsigned* __restrict__ slot, int8_t* __restrict__ Q,
    float* __restrict__ T, int K) {
  int lane = threadIdx.x & 63, wave = threadIdx.x >> 6;
  int row0 = blockIdx.x * 16;
  int r = lane & 15, g = lane >> 4;
  float inv = 127.f / fmaxf(__uint_as_float(*slot), 1e-8f);

  int kPerWave = K >> 3;
  int kbase = wave * kPerWave;
  const float* xrow = X + (long)(row0 + r) * K;
  int8_t* qrow = Q + (long)(row0 + r) * K;

  f32x4 acc = {0.f, 0.f, 0.f, 0.f};
  int nsteps = kPerWave >> 4;
#pragma unroll 4
  for (int s = 0; s < nsteps; s++) {
    int k = kbase + s * 16 + g * 4;
    float4 v = *(const float4*)(xrow + k);
    int b0 = (int)fminf(fmaxf(rintf(v.x * inv), -127.f), 127.f);
    int b1 = (int)fminf(fmaxf(rintf(v.y * inv), -127.f), 127.f);
    int b2 = (int)fminf(fmaxf(rintf(v.z * inv), -127.f), 127.f);
    int b3 = (int)fminf(fmaxf(rintf(v.w * inv), -127.f), 127.f);
    *(int*)(qrow + k) = (b0 & 0xff) | ((b1 & 0xff) << 8) | ((b2 & 0xff) << 16) | ((b3 & 0xff) << 24);
    f16x4 a;
    a[0] = (_Float16)v.x; a[1] = (_Float16)v.y; a[2] = (_Float16)v.z; a[3] = (_Float16)v.w;
    int gs = (kbase + s * 16) >> 4;
    f16x4 b = *(const f16x4*)(Bpre + ((long)gs * 64 + lane) * 4);
    acc = __builtin_amdgcn_mfma_f32_16x16x16f16(a, b, acc, 0, 0, 0);
  }

  __shared__ float part[8][16][17];
#pragma unroll
  for (int j = 0; j < 4; j++) part[wave][g * 4 + j][r] = acc[j];
  __syncthreads();
  int t = threadIdx.x;
  if (t < 256) {
    int m = t >> 4, rr = t & 15;
    float sum = 0.f;
#pragma unroll
    for (int w = 0; w < 8; w++) sum += part[w][m][rr];
    T[(long)(row0 + m) * 16 + rr] = 2.0f * sum;  // LORA_SCALE = 32/16 = 2
  }
}

// ---------------- int8 GEMM, 32x32 MFMA, R8 counted-vmcnt pipeline ----------------
// BM=256, BN=NFR*128, BK=128, 512 thr / 8 waves (2M x 4N), per-wave 128 x NFR*32.
// mfma_i32_32x32x32_i8: half the instructions/ds_reads of 16x16x64 at +14% pipe ceiling.
// A frag: lane row=l&31, 16B at k=ks*32+(l>>5)*16. C/D: col=l&31,
// row=(reg&3)+8*(reg>>2)+4*(l>>5) [m74/m101]. XOR-swizzled LDS (slot c -> c^(row&7),
// inverse-permuted global source); frag addr walks ks via aoff ^ (ks<<5) (carry-free).
// Pipeline per tile kt: p0 issue B(kt+1); compute (4 ks, setprio-wrapped); barrier;
// issue A(kt+2) into kt's A buf; vmcnt(4) [only A(kt+2) outstanding]; barrier.
template <bool GELU, int NFR>
__global__ __launch_bounds__(512) void gemm32(
    const int8_t* __restrict__ Aq, const int8_t* __restrict__ Bq,
    int N, int K,
    const unsigned* __restrict__ sa, const unsigned* __restrict__ sb,
    const float* __restrict__ bias,
    const float* __restrict__ T,   // [M][16], pre-scaled by LORA_SCALE
    const float* __restrict__ Bl,  // [N][16]
    float* __restrict__ C, unsigned* hmax) {
  constexpr int BN = NFR * 128;
  constexpr int ABYTES = 32768;          // 256 rows x 128B
  constexpr int BBYTES = BN * 128;
  constexpr int BL = BBYTES / 16 / 512;  // B glls per thread (4 or 2)
  __shared__ __align__(16) int8_t lds[2 * ABYTES + 2 * BBYTES];
  int8_t* ldsA = lds;
  int8_t* ldsB = lds + 2 * ABYTES;

  // bijective XCD swizzle (nwg = 512 / 256, %8==0)
  int nwg = gridDim.x * gridDim.y;
  int lid = blockIdx.y * gridDim.x + blockIdx.x;
  int cpx = nwg >> 3;
  int nid = (lid & 7) * cpx + (lid >> 3);
  int bn = (nid % gridDim.x) * BN;
  int bm = (nid / gridDim.x) * 256;

  int t = threadIdx.x;
  int lane = t & 63, wave = t >> 6;
  int wr = wave >> 2, wc = wave & 3;    // 2 x 4 wave grid
  int l31 = lane & 31, l5 = lane >> 5;

  const int8_t* gA = Aq + (long)bm * K;
  const int8_t* gB = Bq + (long)bn * K;

  // staging maps: slot s -> row=s>>3, lds col=s&7, global col=(s&7)^(row&7)
  int aDst[4]; long aSrc[4];
#pragma unroll
  for (int i = 0; i < 4; i++) {
    int s = i * 512 + t, row = s >> 3;
    aDst[i] = s * 16;
    aSrc[i] = (long)row * K + (((s & 7) ^ (row & 7)) << 4);
  }
  int bDst[BL]; long bSrc[BL];
#pragma unroll
  for (int i = 0; i < BL; i++) {
    int s = i * 512 + t, row = s >> 3;
    bDst[i] = s * 16;
    bSrc[i] = (long)row * K + (((s & 7) ^ (row & 7)) << 4);
  }

  // fragment read offsets (swizzled); k-step applied via ^ (ks<<5)
  int aoff[4], boff[NFR];
#pragma unroll
  for (int mf = 0; mf < 4; mf++) {
    int row = wr * 128 + mf * 32 + l31;
    aoff[mf] = row * 128 + ((l5 ^ (row & 7)) << 4);
  }
#pragma unroll
  for (int nf = 0; nf < NFR; nf++) {
    int row = wc * (NFR * 32) + nf * 32 + l31;
    boff[nf] = row * 128 + ((l5 ^ (row & 7)) << 4);
  }

  i32x16 acc[4][NFR] = {};
  int KT = K >> 7;

  // prologue: tile0 A+B, tile1 A. vmcnt(4) -> tile0 resident (tile1 A in flight).
#pragma unroll
  for (int i = 0; i < 4; i++) async_lds16(ldsA + aDst[i], gA + aSrc[i]);
#pragma unroll
  for (int i = 0; i < BL; i++) async_lds16(ldsB + bDst[i], gB + bSrc[i]);
#pragma unroll
  for (int i = 0; i < 4; i++) async_lds16(ldsA + ABYTES + aDst[i], gA + aSrc[i] + 128);
  asm volatile("s_waitcnt vmcnt(4)" ::: "memory");
  __builtin_amdgcn_s_barrier();
  __builtin_amdgcn_sched_barrier(0);

  for (int kt = 0; kt < KT; ++kt) {
    const int8_t* Ab = ldsA + (kt & 1) * ABYTES;
    const int8_t* Bb = ldsB + (kt & 1) * BBYTES;

    // p0: issue next tile's B loads into the other B buffer
    if (kt + 1 < KT) {
      long ko = (long)(kt + 1) * 128;
      int nb = ((kt + 1) & 1) * BBYTES;
#pragma unroll
      for (int i = 0; i < BL; i++) async_lds16(ldsB + nb + bDst[i], gB + bSrc[i] + ko);
    }

#pragma unroll
    for (int ks = 0; ks < 4; ks++) {
      int kx = ks << 5;
      i32x4 av[4], bv[NFR];
#pragma unroll
      for (int mf = 0; mf < 4; mf++) av[mf] = *(const i32x4*)(Ab + (aoff[mf] ^ kx));
#pragma unroll
      for (int nf = 0; nf < NFR; nf++) bv[nf] = *(const i32x4*)(Bb + (boff[nf] ^ kx));
      __builtin_amdgcn_s_setprio(1);
#pragma unroll
      for (int mf = 0; mf < 4; mf++)
#pragma unroll
        for (int nf = 0; nf < NFR; nf++)
          acc[mf][nf] = __builtin_amdgcn_mfma_i32_32x32x32_i8(av[mf], bv[nf], acc[mf][nf], 0, 0, 0);
      __builtin_amdgcn_s_setprio(0);
    }

    __builtin_amdgcn_sched_barrier(0);
    __builtin_amdgcn_s_barrier();  // all waves done reading kt's buffers
    if (kt + 2 < KT) {
      long ko = (long)(kt + 2) * 128;
      int nb = (kt & 1) * ABYTES;  // kt's A buffer, now free
#pragma unroll
      for (int i = 0; i < 4; i++) async_lds16(ldsA + nb + aDst[i], gA + aSrc[i] + ko);
      asm volatile("s_waitcnt vmcnt(4)" ::: "memory");  // kt+1 landed; kt+2 A in flight
      __builtin_amdgcn_s_barrier();
      __builtin_amdgcn_sched_barrier(0);
    } else if (kt + 1 < KT) {
      asm volatile("s_waitcnt vmcnt(0)" ::: "memory");
      __builtin_amdgcn_s_barrier();
      __builtin_amdgcn_sched_barrier(0);
    }
  }

  // -------- epilogue: scale + bias + LoRA-up (32x32x16 f16) + optional GELU --------
  float s = (fmaxf(__uint_as_float(*sa), 1e-8f) * (1.f / 127.f)) *
            (fmaxf(__uint_as_float(*sb), 1e-8f) * (1.f / 127.f));

  // T fragments: lane holds T[mBase + l31][l5*8 .. l5*8+8) as f16x8
  f16x8 tf[4];
#pragma unroll
  for (int mf = 0; mf < 4; mf++) {
    int m = bm + wr * 128 + mf * 32 + l31;
    float4 t0 = *(const float4*)(T + (long)m * 16 + l5 * 8);
    float4 t1 = *(const float4*)(T + (long)m * 16 + l5 * 8 + 4);
    f16x8 v;
    v[0] = (_Float16)t0.x; v[1] = (_Float16)t0.y; v[2] = (_Float16)t0.z; v[3] = (_Float16)t0.w;
    v[4] = (_Float16)t1.x; v[5] = (_Float16)t1.y; v[6] = (_Float16)t1.z; v[7] = (_Float16)t1.w;
    tf[mf] = v;
  }
  f16x8 bfr[NFR];
  float bias_v[NFR];
#pragma unroll
  for (int nf = 0; nf < NFR; nf++) {
    int n = bn + wc * (NFR * 32) + nf * 32 + l31;
    float4 b0 = *(const float4*)(Bl + (long)n * 16 + l5 * 8);
    float4 b1 = *(const float4*)(Bl + (long)n * 16 + l5 * 8 + 4);
    f16x8 v;
    v[0] = (_Float16)b0.x; v[1] = (_Float16)b0.y; v[2] = (_Float16)b0.z; v[3] = (_Float16)b0.w;
    v[4] = (_Float16)b1.x; v[5] = (_Float16)b1.y; v[6] = (_Float16)b1.z; v[7] = (_Float16)b1.w;
    bfr[nf] = v;
    bias_v[nf] = bias[n];
  }

  float lmax = 0.f;
#pragma unroll
  for (int mf = 0; mf < 4; mf++) {
#pragma unroll
    for (int nf = 0; nf < NFR; nf++) {
      f32x16 fa = __builtin_amdgcn_mfma_f32_32x32x16_f16(tf[mf], bfr[nf], (f32x16){}, 0, 0, 0);
      int n = bn + wc * (NFR * 32) + nf * 32 + l31;
#pragma unroll
      for (int reg = 0; reg < 16; reg++) {
        int row = (reg & 3) + 8 * (reg >> 2) + 4 * l5;
        int m = bm + wr * 128 + mf * 32 + row;
        float v = s * (float)acc[mf][nf][reg] + bias_v[nf] + fa[reg];
        if constexpr (GELU) {
          v = 0.5f * v * (1.0f + erff(v * 0.70710678118654752f));
          lmax = fmaxf(lmax, fabsf(v));
        }
        C[(long)m * N + n] = v;
      }
    }
  }
  if constexpr (GELU) {
    for (int o = 32; o; o >>= 1) lmax = fmaxf(lmax, __shfl_xor(lmax, o));
    if (lane == 0) atomicMax(hmax, __float_as_uint(lmax));
  }
}

// ---------------- launch ----------------
extern "C" void kernel_launch(void* const* d_in, const int* in_sizes, int n_in,
                              void* d_out, int out_size, void* d_ws, size_t ws_size,
                              hipStream_t stream) {
  const float* x   = (const float*)d_in[0];
  const float* Wfc = (const float*)d_in[1];
  const float* bfc = (const float*)d_in[2];
  const float* Afc = (const float*)d_in[3];
  const float* Bfc = (const float*)d_in[4];
  const float* Wpj = (const float*)d_in[5];
  const float* bpj = (const float*)d_in[6];
  const float* Apj = (const float*)d_in[7];
  const float* Bpj = (const float*)d_in[8];
  float* out = (float*)d_out;

  char* ws = (char*)d_ws;
  unsigned* slots = (unsigned*)ws;  // [0]=max|x| [1]=max|Wfc| [2]=max|Wpj| [3]=max|h|
  int8_t* qx  = (int8_t*)(ws + 256);
  int8_t* qwf = qx  + (size_t)M_TOK * N_EMB;
  int8_t* qwp = qwf + (size_t)D_FF * N_EMB;
  int8_t* qh  = qwp + (size_t)N_EMB * D_FF;
  float*  t1  = (float*)(qh + (size_t)M_TOK * D_FF);
  float*  t2  = t1  + (size_t)M_TOK * 16;
  _Float16* Bp1 = (_Float16*)(t2 + (size_t)M_TOK * 16);
  _Float16* Bp2 = Bp1 + (size_t)N_EMB * 16;
  float*  h   = (float*)(Bp2 + (size_t)D_FF * 16);

  zero_slots_k<<<1, 64, 0, stream>>>(slots);
  absmax_k<<<1024, 256, 0, stream>>>(x,   (long)M_TOK * N_EMB, slots + 0);
  absmax_k<<<1024, 256, 0, stream>>>(Wfc, (long)D_FF * N_EMB,  slots + 1);
  absmax_k<<<1024, 256, 0, stream>>>(Wpj, (long)N_EMB * D_FF,  slots + 2);

  quant_k<<<2048, 256, 0, stream>>>(Wfc, qwf, (long)D_FF * N_EMB, slots + 1);
  quant_k<<<2048, 256, 0, stream>>>(Wpj, qwp, (long)N_EMB * D_FF, slots + 2);

  prep_bfrag_k<<<N_EMB / 16, 64, 0, stream>>>(Afc, Bp1, N_EMB);
  prep_bfrag_k<<<D_FF / 16, 64, 0, stream>>>(Apj, Bp2, D_FF);

  lora_quant_k<<<M_TOK / 16, 512, 0, stream>>>(x, Bp1, slots + 0, qx, t1, N_EMB);

  // GEMM1: 256x256 tiles -> grid (16, 32) = 512 blocks
  gemm32<true, 2><<<dim3(D_FF / 256, M_TOK / 256), 512, 0, stream>>>(
      qx, qwf, D_FF, N_EMB, slots + 0, slots + 1, bfc, t1, Bfc, h, slots + 3);

  lora_quant_k<<<M_TOK / 16, 512, 0, stream>>>(h, Bp2, slots + 3, qh, t2, D_FF);

  // GEMM2: 256x128 tiles -> grid (8, 32) = 256 blocks
  gemm32<false, 1><<<dim3(N_EMB / 128, M_TOK / 256), 512, 0, stream>>>(
      qh, qwp, N_EMB, D_FF, slots + 3, slots + 2, bpj, t2, Bpj, out, nullptr);
}